// Round 1
// 574.606 us; speedup vs baseline: 1.3081x; 1.3081x over previous
//
#include <hip/hip_runtime.h>
#include <math.h>
#include <float.h>

#define B_   16
#define N_   4096
#define CIN  3
#define COUT 64
#define KNN  20
#define EPS_ 1e-5

// ---------------------------------------------------------------------------
// Workspace layout:
//   [0,   216): double stats[27]    (Sum e[6], Sum e e^T upper-tri[21])
//   [256, 768): float scale[64], shift[64]
//   [1024, 1024 + B*N*KNN*4): int idx[B*N*KNN]           (5242880 B)
//   [5243904, +B*N*4): int perm[B*N]  (Morton row order)  (262144 B)
// ---------------------------------------------------------------------------

__device__ __forceinline__ unsigned expand10(unsigned v) {
    v = (v | (v << 16)) & 0x030000FFu;
    v = (v | (v << 8))  & 0x0300F00Fu;
    v = (v | (v << 4))  & 0x030C30C3u;
    v = (v | (v << 2))  & 0x09249249u;
    return v;
}
__device__ __forceinline__ unsigned quant10(float v) {
    int q = (int)((v + 4.0f) * 128.0f);
    return (unsigned)min(1023, max(0, q));
}

// ===========================================================================
// Kernel 0: per-batch Morton COUNTING sort (unchanged)
// ===========================================================================
__global__ __launch_bounds__(1024) void morton_bucket_kernel(
    const float* __restrict__ x, int* __restrict__ perm)
{
    __shared__ int hist[1024];
    __shared__ int scanbuf[1024];
    __shared__ int offs[1024];
    const int b = blockIdx.x, tid = threadIdx.x;
    const float* xb = x + (size_t)b * N_ * CIN;

    hist[tid] = 0;
    __syncthreads();

    int keys[4];
#pragma unroll
    for (int i = 0; i < 4; ++i) {
        int p = tid + i * 1024;
        float v0 = xb[p * 3 + 0], v1 = xb[p * 3 + 1], v2 = xb[p * 3 + 2];
        unsigned m = (expand10(quant10(v0)) << 2) |
                     (expand10(quant10(v1)) << 1) |
                      expand10(quant10(v2));
        keys[i] = (int)(m >> 20);          // top 10 bits
        atomicAdd(&hist[keys[i]], 1);
    }
    __syncthreads();

    int v = hist[tid];
    scanbuf[tid] = v;
    __syncthreads();
    for (int off = 1; off < 1024; off <<= 1) {   // Hillis-Steele inclusive
        int t = (tid >= off) ? scanbuf[tid - off] : 0;
        __syncthreads();
        scanbuf[tid] += t;
        __syncthreads();
    }
    offs[tid] = scanbuf[tid] - v;                // exclusive base
    __syncthreads();

#pragma unroll
    for (int i = 0; i < 4; ++i) {
        int p = tid + i * 1024;
        int pos = atomicAdd(&offs[keys[i]], 1);
        perm[b * N_ + pos] = p;
    }
}

// ===========================================================================
// Kernel 1: exact-match KNN (unchanged — verified structure, ~370us)
// ===========================================================================
__global__ __launch_bounds__(512) void knn_f64_kernel(
    const float* __restrict__ x, const int* __restrict__ perm,
    int* __restrict__ idx_out, double* __restrict__ stats)
{
    __shared__ __align__(16) char smem[65536];
    float4* pts = (float4*)smem;                 // {x,y,z,bitcast(j)}
    double* scr = (double*)smem;                 // merge-scratch view

    const int b    = blockIdx.y;
    const int tid  = threadIdx.x;
    const int wave = tid >> 6;
    const int lane = tid & 63;
    const int r    = wave >> 2;     // row-group 0..1
    const int q    = wave & 3;      // interleave class: positions p&3==q
    const float* xb = x + (size_t)b * N_ * CIN;

    for (int p = tid; p < N_; p += 512) {
        int j = perm[b * N_ + p];                // coalesced
        pts[p] = make_float4(xb[j * 3 + 0], xb[j * 3 + 1], xb[j * 3 + 2],
                             __int_as_float(j));
    }
    __syncthreads();

    const int rowg = blockIdx.x * 128 + r * 64;  // wave's first row pos
    const float4 xf = pts[rowg + lane];
    const int jrow  = __float_as_int(xf.w);
    const float sqi = __fadd_rn(__fadd_rn(__fmul_rn(xf.x, xf.x),
                                          __fmul_rn(xf.y, xf.y)),
                                __fmul_rn(xf.z, xf.z));

    auto mkkey = [&](float4 p) -> double {
        float sqj = __fadd_rn(__fadd_rn(__fmul_rn(p.x, p.x),
                                        __fmul_rn(p.y, p.y)),
                              __fmul_rn(p.z, p.z));
        float dot = __fadd_rn(__fadd_rn(__fmul_rn(xf.x, p.x),
                                        __fmul_rn(xf.y, p.y)),
                              __fmul_rn(xf.z, p.z));
        float d = __fsub_rn(__fadd_rn(sqi, sqj), __fmul_rn(2.0f, dot));
        unsigned u = __float_as_uint(d);
        unsigned s = u ^ (0x80000000u | (unsigned)((int)u >> 31));
        return fma((double)s, 4096.0,
                   (double)(unsigned)__float_as_int(p.w));
    };

    double bk[KNN];
#pragma unroll
    for (int k = 0; k < KNN; ++k) bk[k] = 1e300;     // sentinels (sorted)

    auto insert = [&](double key) {
        if (key < bk[KNN - 1]) {
            double m = key;                  // carries max(bk_old[i-1], key)
#pragma unroll
            for (int k = 0; k < KNN; ++k) {
                double old = bk[k];
                bk[k] = fmin(m, old);
                m     = fmax(old, m);
            }
        }
    };

    const int ta = rowg >> 2;            // wave-uniform anchor (SGPR math)
#pragma unroll
    for (int k = 0; k < KNN; ++k)
        insert(mkkey(pts[4 * ((ta + k) & 1023) + q]));

    for (int s = 0; s < 1024; s += 4) {
        int v0 = ((s + 0) * 509) & 1023;
        int v1 = ((s + 1) * 509) & 1023;
        int v2 = ((s + 2) * 509) & 1023;
        int v3 = ((s + 3) * 509) & 1023;
        float4 a0 = pts[4 * ((ta + v0) & 1023) + q];
        float4 a1 = pts[4 * ((ta + v1) & 1023) + q];
        float4 a2 = pts[4 * ((ta + v2) & 1023) + q];
        float4 a3 = pts[4 * ((ta + v3) & 1023) + q];
        double k0 = (v0 < 20) ? 1e300 : mkkey(a0);
        double k1 = (v1 < 20) ? 1e300 : mkkey(a1);
        double k2 = (v2 < 20) ? 1e300 : mkkey(a2);
        double k3 = (v3 < 20) ? 1e300 : mkkey(a3);
        double w = bk[KNN - 1];          // stale for the check: over-enters only
        if ((k0 < w) | (k1 < w) | (k2 < w) | (k3 < w)) {
            insert(k0); insert(k1); insert(k2); insert(k3);
        }
    }
    __syncthreads();    // scans done; pts dead (xf in regs) -> scr valid

    if (q & 1) {
        int base = ((r * 2 + (q >> 1)) * 64 + lane) * KNN;
#pragma unroll
        for (int k = 0; k < KNN; ++k) scr[base + k] = bk[k];
    }
    __syncthreads();
    if (!(q & 1)) {                 // q0 absorbs q1; q2 absorbs q3
        int base = ((r * 2 + (q >> 1)) * 64 + lane) * KNN;
#pragma unroll
        for (int k = 0; k < KNN; ++k) insert(scr[base + k]);
    }
    __syncthreads();
    if (q == 2) {
        int base = ((r * 2 + 1) * 64 + lane) * KNN;
#pragma unroll
        for (int k = 0; k < KNN; ++k) scr[base + k] = bk[k];
    }
    __syncthreads();
    if (q == 0) {
        int base = ((r * 2 + 1) * 64 + lane) * KNN;
#pragma unroll
        for (int k = 0; k < KNN; ++k) insert(scr[base + k]);

        const long long row = (long long)b * N_ + jrow;
        int bi[KNN];
#pragma unroll
        for (int k = 0; k < KNN; ++k) {
            double sp = trunc(bk[k] * (1.0 / 4096.0));
            bi[k] = (int)(bk[k] - sp * 4096.0);
        }
#pragma unroll
        for (int k = 0; k < KNN; ++k) idx_out[row * KNN + k] = bi[k];

        float acc[27];
#pragma unroll
        for (int t = 0; t < 27; ++t) acc[t] = 0.0f;
#pragma unroll
        for (int k = 0; k < KNN; ++k) {
            const float* pj = xb + bi[k] * 3;
            float e[6] = { xf.x, xf.y, xf.z,
                           pj[0] - xf.x, pj[1] - xf.y, pj[2] - xf.z };
            int t = 6;
#pragma unroll
            for (int a = 0; a < 6; ++a) {
                acc[a] += e[a];
#pragma unroll
                for (int bb = a; bb < 6; ++bb) acc[t++] += e[a] * e[bb];
            }
        }
#pragma unroll
        for (int t = 0; t < 27; ++t) {
            float v = acc[t];
            v += __shfl_down(v, 32); v += __shfl_down(v, 16);
            v += __shfl_down(v, 8);  v += __shfl_down(v, 4);
            v += __shfl_down(v, 2);  v += __shfl_down(v, 1);
            acc[t] = v;
        }
        if (lane == 0) {
#pragma unroll
            for (int t = 0; t < 27; ++t) atomicAdd(&stats[t], (double)acc[t]);
        }
    }
}

// ===========================================================================
// Kernel 2: fold stats -> per-channel scale/shift (unchanged)
// ===========================================================================
__global__ void bn_prep_kernel(
    const double* __restrict__ stats,
    const float* __restrict__ w1, const float* __restrict__ b1,
    const float* __restrict__ gamma, const float* __restrict__ beta,
    float* __restrict__ scale_shift)
{
    const int c = threadIdx.x;
    double s[6], S[6][6];
#pragma unroll
    for (int a = 0; a < 6; ++a) s[a] = stats[a];
    int t = 6;
#pragma unroll
    for (int a = 0; a < 6; ++a)
#pragma unroll
        for (int bb = a; bb < 6; ++bb) { S[a][bb] = stats[t]; S[bb][a] = stats[t]; ++t; }

    const double M = (double)B_ * N_ * KNN;
    double wc[6];
#pragma unroll
    for (int j = 0; j < 6; ++j) wc[j] = (double)w1[j * COUT + c];
    const double b1c = (double)b1[c];

    double sw = 0.0;
#pragma unroll
    for (int j = 0; j < 6; ++j) sw += s[j] * wc[j];
    double mean = sw / M + b1c;

    double qq = 0.0;
#pragma unroll
    for (int a = 0; a < 6; ++a)
#pragma unroll
        for (int bb = 0; bb < 6; ++bb) qq += S[a][bb] * wc[a] * wc[bb];
    double ex2 = (qq + 2.0 * b1c * sw) / M + b1c * b1c;
    double var = ex2 - mean * mean;

    double sc = (double)gamma[c] / sqrt(var + (double)EPS_);
    double sh = (double)beta[c] - mean * sc;
    scale_shift[c]        = (float)sc;
    scale_shift[COUT + c] = (float)sh;
}

// ===========================================================================
// Kernel 3 (REWRITTEN): fused edge->lin1->BN->ReLU->lin2->max via split-bf16
// MFMA. Old version was LDS-broadcast-bound (~21 GB LDS->VGPR traffic,
// MfmaUtil=0). New dataflow:
//   - 4 waves/block, 16 rows/wave, wave-private LDS (NO barriers).
//   - phase 1 (VALU, fp32): h = relu((e@w1+b1)*sc+sh) with BN folded into
//     w1' = w1*sc, b1' = b1*sc+sh, and the xi part hoisted out of the k-loop
//     (base[r]); 3 FMA per h value. lane = channel.
//   - h split hi/lo bf16, written to a 272B-pitch LDS tile (double-buffered
//     over k), read back as 16x16x32 A-fragments.
//   - phase 2 (MFMA): C_k = Hh@Wh + Hh@Wl + Hl@Wh  (split-bf16 ~ fp32 to
//     1e-4), 24 MFMAs per (k, 16 rows); running fmax over k; +b2 at end.
// ===========================================================================
typedef __attribute__((ext_vector_type(8))) short short8;
typedef __attribute__((ext_vector_type(4))) float f32x4;

__device__ __forceinline__ unsigned short f2bf_rn(float f) {
    unsigned u = __float_as_uint(f);
    unsigned lsb = (u >> 16) & 1u;
    return (unsigned short)((u + 0x7FFFu + lsb) >> 16);
}
__device__ __forceinline__ float bf2f(unsigned short h) {
    return __uint_as_float(((unsigned)h) << 16);
}

__global__ __launch_bounds__(256) void mlp_max_kernel(
    const float* __restrict__ x, const int* __restrict__ idx,
    const float* __restrict__ w1, const float* __restrict__ b1,
    const float* __restrict__ scale_shift,
    const float* __restrict__ w2, const float* __restrict__ b2,
    float* __restrict__ out)
{
    // per-wave double-buffered H tile: [wave][buf][row][136 ushort]
    //   row pitch 272 B (17x16B) -> balanced banks on b128 frag reads.
    //   hi plane at [0,64), lo plane at [64,128), pad [128,136).
    __shared__ __align__(16) unsigned short hbuf[4][2][16][136];

    const int tid  = threadIdx.x;
    const int wv   = tid >> 6;
    const int lane = tid & 63;
    const int g    = lane >> 4;      // 16-lane group (k-chunk select)
    const int r15  = lane & 15;      // row (A) / col (B,C) within tile

    const int R     = (blockIdx.x * 4 + wv) * 16;   // wave's first row
    const int bbase = (R >> 12) << 12;              // batch slab start row

    // ---- per-channel folded weights (lane = channel c) ----
    const int c  = lane;
    const float sc = scale_shift[c];
    const float sh = scale_shift[COUT + c];
    float w1p[6];
#pragma unroll
    for (int j = 0; j < 6; ++j) w1p[j] = w1[j * COUT + c] * sc;
    const float b1p = fmaf(b1[c], sc, sh);
    const float dw0 = w1p[0] - w1p[3];
    const float dw1 = w1p[1] - w1p[4];
    const float dw2 = w1p[2] - w1p[5];

    // ---- W2 fragments, split hi/lo bf16, B-layout for 16x16x32 ----
    // B[kd][col]: lane holds kd = 32t + 8g + j, col = 16n + r15.
    short8 Wh[2][4], Wl[2][4];
#pragma unroll
    for (int t = 0; t < 2; ++t)
#pragma unroll
        for (int n = 0; n < 4; ++n) {
            short8 hv, lv;
#pragma unroll
            for (int jj = 0; jj < 8; ++jj) {
                float w = w2[(t * 32 + g * 8 + jj) * COUT + n * 16 + r15];
                unsigned short hi = f2bf_rn(w);
                unsigned short lo = f2bf_rn(w - bf2f(hi));
                hv[jj] = (short)hi;
                lv[jj] = (short)lo;
            }
            Wh[t][n] = hv;
            Wl[t][n] = lv;
        }

    // ---- xi-dependent base per row (hoisted out of k-loop) ----
    float base[16];
#pragma unroll
    for (int r = 0; r < 16; ++r) {
        const float* pi = x + (size_t)(R + r) * 3;
        float v = b1p;
        v = fmaf(pi[0], dw0, v);
        v = fmaf(pi[1], dw1, v);
        v = fmaf(pi[2], dw2, v);
        base[r] = v;
    }

    const int* idxp = idx + (size_t)R * KNN;

    f32x4 mx[4];
#pragma unroll
    for (int n = 0; n < 4; ++n) {
        mx[n][0] = -INFINITY; mx[n][1] = -INFINITY;
        mx[n][2] = -INFINITY; mx[n][3] = -INFINITY;
    }

    for (int k = 0; k < KNN; ++k) {
        unsigned short* hb = &hbuf[wv][k & 1][0][0];

        // phase 1: 16 rows x 64 ch of h, split to bf16 hi/lo in LDS
#pragma unroll
        for (int r = 0; r < 16; ++r) {
            int j = idxp[r * KNN + k];                    // wave-uniform
            const float* pj = x + (size_t)(bbase + j) * 3;
            float h = base[r];
            h = fmaf(pj[0], w1p[3], h);
            h = fmaf(pj[1], w1p[4], h);
            h = fmaf(pj[2], w1p[5], h);
            h = fmaxf(h, 0.0f);
            unsigned short hi = f2bf_rn(h);
            unsigned short lo = f2bf_rn(h - bf2f(hi));
            hb[r * 136 + c]      = hi;
            hb[r * 136 + 64 + c] = lo;
        }

        // phase 2: A-fragments (row = r15, kd = 32t + 8g + j)
        const unsigned short* rp = hb + r15 * 136;
        short8 Ah0 = *(const short8*)(rp + g * 8);
        short8 Ah1 = *(const short8*)(rp + 32 + g * 8);
        short8 Al0 = *(const short8*)(rp + 64 + g * 8);
        short8 Al1 = *(const short8*)(rp + 96 + g * 8);

#pragma unroll
        for (int n = 0; n < 4; ++n) {
            f32x4 a = {0.0f, 0.0f, 0.0f, 0.0f};
            a = __builtin_amdgcn_mfma_f32_16x16x32_bf16(Ah0, Wh[0][n], a, 0, 0, 0);
            a = __builtin_amdgcn_mfma_f32_16x16x32_bf16(Ah1, Wh[1][n], a, 0, 0, 0);
            a = __builtin_amdgcn_mfma_f32_16x16x32_bf16(Al0, Wh[0][n], a, 0, 0, 0);
            a = __builtin_amdgcn_mfma_f32_16x16x32_bf16(Al1, Wh[1][n], a, 0, 0, 0);
            a = __builtin_amdgcn_mfma_f32_16x16x32_bf16(Ah0, Wl[0][n], a, 0, 0, 0);
            a = __builtin_amdgcn_mfma_f32_16x16x32_bf16(Ah1, Wl[1][n], a, 0, 0, 0);
            mx[n][0] = fmaxf(mx[n][0], a[0]);
            mx[n][1] = fmaxf(mx[n][1], a[1]);
            mx[n][2] = fmaxf(mx[n][2], a[2]);
            mx[n][3] = fmaxf(mx[n][3], a[3]);
        }
    }

    // epilogue: + b2, store. C/D: col = 16n + r15, row = 4g + reg.
    float b2v[4];
#pragma unroll
    for (int n = 0; n < 4; ++n) b2v[n] = b2[n * 16 + r15];
#pragma unroll
    for (int n = 0; n < 4; ++n)
#pragma unroll
        for (int rr = 0; rr < 4; ++rr)
            out[(size_t)(R + g * 4 + rr) * COUT + n * 16 + r15] =
                mx[n][rr] + b2v[n];
}

// ===========================================================================
extern "C" void kernel_launch(void* const* d_in, const int* in_sizes, int n_in,
                              void* d_out, int out_size, void* d_ws, size_t ws_size,
                              hipStream_t stream)
{
    const float* x     = (const float*)d_in[0];
    const float* w1    = (const float*)d_in[2];
    const float* b1    = (const float*)d_in[3];
    const float* gamma = (const float*)d_in[4];
    const float* beta  = (const float*)d_in[5];
    const float* w2    = (const float*)d_in[6];
    const float* b2    = (const float*)d_in[7];
    float* out = (float*)d_out;

    char*   ws          = (char*)d_ws;
    double* stats       = (double*)ws;
    float*  scale_shift = (float*)(ws + 256);
    int*    idx         = (int*)(ws + 1024);
    int*    perm        = (int*)(ws + 1024 + (size_t)B_ * N_ * KNN * 4);

    hipMemsetAsync(stats, 0, 27 * sizeof(double), stream);
    morton_bucket_kernel<<<B_, 1024, 0, stream>>>(x, perm);
    knn_f64_kernel<<<dim3(32, 16), 512, 0, stream>>>(x, perm, idx, stats);
    bn_prep_kernel<<<1, COUT, 0, stream>>>(stats, w1, b1, gamma, beta, scale_shift);
    mlp_max_kernel<<<(B_ * N_) / 64, 256, 0, stream>>>(x, idx, w1, b1, scale_shift,
                                                       w2, b2, out);
}